// Round 3
// baseline (585.997 us; speedup 1.0000x reference)
//
#include <hip/hip_runtime.h>
#include <hip/hip_bf16.h>

// ---------------------------------------------------------------------------
// concat(x1,x2) -> LSTM(551->128, T=5) -> MLP 640->531->256->64->2 -> softmax
// B=16384, T=5, IN=551, H=128. bf16 MFMA 16x16x32, fp32 accum.
// R5: within-probe A/B on x-prefetch depth.
//   k1_xgemm  = R4 control (unchanged, depth-2).
//   k1_deep   = depth-6 x prefetch in registers (P[6] rotation, fully
//               unrolled 18 steps), B-tiles 2-ahead in 3-buffer LDS via
//               global_load_lds, exact vmcnt immediates (6/4/0), lgkmcnt(0)
//               before every raw barrier. Runs AFTER control, overwrites xg.
// Packed B/A-tile layout: 16(n|m) x 32(k) tile = 512 elems, element
//   (n,k) -> tile(tn=n>>4, tk=k>>5) at offset lane*8+j, lane=((k>>3)&3)*16+(n&15), j=k&7.
// Packed C-tile layout: 16x16 tile = 256 elems, (m,n) -> offset lane*4+r,
//   lane=((m>>2)&3)*16+(n&15), r=m&3.   (matches MFMA C layout per lane)
// ---------------------------------------------------------------------------

typedef short  short8  __attribute__((ext_vector_type(8)));
typedef short  short4v __attribute__((ext_vector_type(4)));
typedef float  f32x4   __attribute__((ext_vector_type(4)));

#define MFMA(a, b, c) __builtin_amdgcn_mfma_f32_16x16x32_bf16((a), (b), (c), 0, 0, 0)
#define WAITV(N) asm volatile("s_waitcnt vmcnt(" #N ")" ::: "memory")
#define LGKM0()  asm volatile("s_waitcnt lgkmcnt(0)" ::: "memory")
#define MEMF()   asm volatile("" ::: "memory")
#define BAR()    __builtin_amdgcn_s_barrier()

__device__ __forceinline__ short f2bs(float f) {
    __hip_bfloat16 h = __float2bfloat16(f);   // RNE
    union { __hip_bfloat16 h; short s; } u; u.h = h; return u.s;
}
__device__ __forceinline__ float b2f(short s) {
    union { unsigned u; float f; } v; v.u = ((unsigned)(unsigned short)s) << 16; return v.f;
}
__device__ __forceinline__ float sigf(float x)  { return 1.f / (1.f + __expf(-x)); }
__device__ __forceinline__ float mytanh(float x){ return 2.f / (1.f + __expf(-2.f * x)) - 1.f; }

// async global(16B) -> LDS, lane-linear dest
__device__ __forceinline__ void gload16(const short* g, short* l) {
    __builtin_amdgcn_global_load_lds(
        (const __attribute__((address_space(1))) void*)g,
        (__attribute__((address_space(3))) void*)l, 16, 0, 0);
}

// ---------------- constants ----------------
#define BB     16384
#define TT     5
#define F1     300
#define F2     251
#define INF    551
#define KP     576          // padded K for input GEMM (18 k-tiles)
#define G4     512
#define HH     128
#define FLAT   640          // T*H (20 k-tiles)
#define L1N    531
#define L1P    576
#define L1KP   544          // 17 k-tiles
#define L2N    256
#define L3N    64

// ws offsets (bytes)
#define O_WIH  0u
#define O_WHH  589824u
#define O_W1   720896u
#define O_W2   1458176u
#define O_W3   1736704u
#define O_BG   1769472u
#define O_B1   1771520u
#define O_XG   1773824u
#define O_HS   85659904u
#define WS_NEED 106631424u

// ---------------------------------------------------------------------------
// prep: weights fp32 -> bf16, packed in B-fragment tile order
// ---------------------------------------------------------------------------
__device__ __forceinline__ void pack_b(const float* __restrict__ W, short* __restrict__ dst,
                                       int i, int tpn, int Nsrc, int Ksrc, int ldw)
{
    int tile = i >> 9, rem = i & 511, lane = rem >> 3, jj = rem & 7;
    int tn = tile / tpn, tk = tile - tn * tpn;
    int n = tn * 16 + (lane & 15);
    int k = tk * 32 + (lane >> 4) * 8 + jj;
    float v = (n < Nsrc && k < Ksrc) ? W[n * ldw + k] : 0.f;
    dst[i] = f2bs(v);
}

__global__ void prep_kernel(
    const float* __restrict__ W_ih, const float* __restrict__ W_hh,
    const float* __restrict__ b_ih, const float* __restrict__ b_hh,
    const float* __restrict__ W1,   const float* __restrict__ b1,
    const float* __restrict__ W2,   const float* __restrict__ W3,
    short* __restrict__ Wihp, short* __restrict__ Whhp, float* __restrict__ biasg,
    short* __restrict__ W1p,  float* __restrict__ b1p,  short* __restrict__ W2p,
    short* __restrict__ W3p)
{
    const int N0 = G4 * KP;            // 294912
    const int N1 = N0 + G4 * HH;       // +65536
    const int N2 = N1 + L1P * FLAT;    // +368640
    const int N3 = N2 + L2N * L1KP;    // +139264
    const int N4 = N3 + L3N * L2N;     // +16384
    const int N5 = N4 + G4;
    const int N6 = N5 + L1P;
    const int stride = gridDim.x * blockDim.x;
    for (int i = blockIdx.x * blockDim.x + threadIdx.x; i < N6; i += stride) {
        if (i < N0)      pack_b(W_ih, Wihp, i,       18, G4,  INF, INF);
        else if (i < N1) pack_b(W_hh, Whhp, i - N0,   4, G4,  HH,  HH);
        else if (i < N2) pack_b(W1,   W1p,  i - N1,  20, L1N, FLAT, FLAT);
        else if (i < N3) pack_b(W2,   W2p,  i - N2,  17, L2N, L1N, L1N);
        else if (i < N4) pack_b(W3,   W3p,  i - N3,   8, L3N, L2N, L2N);
        else if (i < N5) { int j = i - N4; biasg[j] = b_ih[j] + b_hh[j]; }
        else             { int j = i - N5; b1p[j] = (j < L1N) ? b1[j] : 0.f; }
    }
}

// ---------------------------------------------------------------------------
// shared helpers for k1 variants
// ---------------------------------------------------------------------------
__device__ __forceinline__ float4 ld4u(const float* __restrict__ x1r,
                                       const float* __restrict__ x2r, int c)
{
    // branchless single-load: c<300 -> x1; else x2 (clamped into row for the
    // dead k>=552 pad region). One global_load_dwordx4 per call, always.
    int c2 = c - F1;
    c2 = (c2 < F2) ? c2 : 0;                  // pad region -> safe garbage
    const float* p = (c < F1) ? (x1r + c) : (x2r + c2);
    return *(const float4*)p;
}

__device__ __forceinline__ void k1_step(const short* __restrict__ Ab8,
                                        const short* __restrict__ Bb8,
                                        int w, int lane, f32x4 (&acc)[8][4])
{
    short8 a[8];
#pragma unroll
    for (int mt = 0; mt < 8; ++mt)
        a[mt] = *(const short8*)&Ab8[mt * 512 + lane * 8];
#pragma unroll
    for (int nt = 0; nt < 4; ++nt) {
        short8 b = *(const short8*)&Bb8[(w * 4 + nt) * 512 + lane * 8];
#pragma unroll
        for (int mt = 0; mt < 8; ++mt)
            acc[mt][nt] = MFMA(a[mt], b, acc[mt][nt]);
    }
}

__device__ __forceinline__ void cvtw(const float4& a, const float4& b, short* d)
{
    short8 v;
    v[0]=f2bs(a.x); v[1]=f2bs(a.y); v[2]=f2bs(a.z); v[3]=f2bs(a.w);
    v[4]=f2bs(b.x); v[5]=f2bs(b.y); v[6]=f2bs(b.z); v[7]=f2bs(b.w);
    *(short8*)d = v;
}

// ---------------------------------------------------------------------------
// k1_xgemm: R4 CONTROL (unchanged). Depth-2 pipeline, counted vmcnt(6).
// ---------------------------------------------------------------------------
__global__ __launch_bounds__(512, 2) void k1_xgemm(
    const float* __restrict__ x1, const float* __restrict__ x2,
    const short* __restrict__ Wihp, const float* __restrict__ biasg,
    short* __restrict__ xg)
{
    __shared__ __align__(16) short Ab[2][8][512];    // 16 KB: A-frag tiles
    __shared__ __align__(16) short Bb[3][32][512];   // 96 KB: B-frag tiles
    const int tid  = threadIdx.x;
    const int w    = tid >> 6;
    const int lane = tid & 63;
    const int c16  = lane & 15;
    const int kq   = lane >> 4;
    const int m0   = blockIdx.x * 128;      // m' = t*B + b; 128 | 16384
    const int t    = m0 >> 14;
    const int bb   = m0 & 16383;

    const int arow = bb + w * 16 + c16;
    const float* x1r = x1 + ((size_t)arow * TT + t) * F1;
    const float* x2r = x2 + ((size_t)arow * TT + t) * F2;
    const int ac0 = kq * 8;

    f32x4 acc[8][4];
#pragma unroll
    for (int mt = 0; mt < 8; ++mt)
#pragma unroll
        for (int nt = 0; nt < 4; ++nt)
            acc[mt][nt] = (f32x4){0.f, 0.f, 0.f, 0.f};

#pragma unroll
    for (int i = 0; i < 4; ++i) {
        int tn = w * 4 + i;
        gload16(Wihp + ((tn * 18 + 0) << 9) + lane * 8, &Bb[0][tn][lane * 8]);
    }
    float4 p0 = ld4u(x1r, x2r, ac0), p1 = ld4u(x1r, x2r, ac0 + 4);
#pragma unroll
    for (int i = 0; i < 4; ++i) {
        int tn = w * 4 + i;
        gload16(Wihp + ((tn * 18 + 1) << 9) + lane * 8, &Bb[1][tn][lane * 8]);
    }
    float4 r0 = ld4u(x1r, x2r, 32 + ac0), r1 = ld4u(x1r, x2r, 32 + ac0 + 4);
    cvtw(p0, p1, &Ab[0][w][lane * 8]);
    WAITV(6); BAR(); MEMF();

    int bS = 2, bR = 0;
    for (int s = 0; s < 16; ++s) {
        const int tk = s + 2;
#pragma unroll
        for (int i = 0; i < 4; ++i) {
            int tn = w * 4 + i;
            gload16(Wihp + ((tn * 18 + tk) << 9) + lane * 8, &Bb[bS][tn][lane * 8]);
        }
        int c = tk * 32 + ac0;
        float4 n0 = ld4u(x1r, x2r, c), n1 = ld4u(x1r, x2r, c + 4);

        k1_step(&Ab[s & 1][0][0], &Bb[bR][0][0], w, lane, acc);

        cvtw(r0, r1, &Ab[(s + 1) & 1][w][lane * 8]);
        r0 = n0; r1 = n1;
        WAITV(6); BAR(); MEMF();
        bS = (bS == 2) ? 0 : bS + 1;
        bR = (bR == 2) ? 0 : bR + 1;
    }

    k1_step(&Ab[0][0][0], &Bb[1][0][0], w, lane, acc);
    cvtw(r0, r1, &Ab[1][w][lane * 8]);
    WAITV(0); BAR(); MEMF();
    k1_step(&Ab[1][0][0], &Bb[2][0][0], w, lane, acc);

#pragma unroll
    for (int nt = 0; nt < 4; ++nt) {
        float bv = biasg[w * 64 + nt * 16 + c16];
#pragma unroll
        for (int mt = 0; mt < 8; ++mt) {
            short4v o;
#pragma unroll
            for (int r = 0; r < 4; ++r) o[r] = f2bs(acc[mt][nt][r] + bv);
            int tm = (m0 >> 4) + mt, tn = w * 4 + nt;
            *(short4v*)&xg[((tm * 32 + tn) << 8) + lane * 4] = o;
        }
    }
}

// ---------------------------------------------------------------------------
// k1_deep: VARIANT. Depth-6 x prefetch in registers, B 2-ahead (3-buffer).
// Fully unrolled 18 steps; per-iter queue order [x(s+6)x2, B(s+2)x4] makes
// WAITV(6) complete exactly B(s+1) while x keeps 5 iters of flight.
// lgkmcnt(0) before every barrier (cross-wave ds_write visibility).
// ---------------------------------------------------------------------------
__global__ __launch_bounds__(512, 2) void k1_deep(
    const float* __restrict__ x1, const float* __restrict__ x2,
    const short* __restrict__ Wihp, const float* __restrict__ biasg,
    short* __restrict__ xg)
{
    __shared__ __align__(16) short Ab[2][8][512];    // 16 KB
    __shared__ __align__(16) short Bb[3][32][512];   // 96 KB
    const int tid  = threadIdx.x;
    const int w    = tid >> 6;
    const int lane = tid & 63;
    const int c16  = lane & 15;
    const int kq   = lane >> 4;
    const int m0   = blockIdx.x * 128;
    const int t    = m0 >> 14;
    const int bb   = m0 & 16383;

    const int arow = bb + w * 16 + c16;
    const float* x1r = x1 + ((size_t)arow * TT + t) * F1;
    const float* x2r = x2 + ((size_t)arow * TT + t) * F2;
    const int ac0 = kq * 8;

    f32x4 acc[8][4];
#pragma unroll
    for (int mt = 0; mt < 8; ++mt)
#pragma unroll
        for (int nt = 0; nt < 4; ++nt)
            acc[mt][nt] = (f32x4){0.f, 0.f, 0.f, 0.f};

    float4 P[6][2];                         // x depth-6 rotation (48 VGPR)

    // ---- prologue: x(0..5), B(0), B(1); cvt+write A(0); wait; barrier ----
#pragma unroll
    for (int d = 0; d < 6; ++d) {
        int c = d * 32 + ac0;
        P[d][0] = ld4u(x1r, x2r, c);
        P[d][1] = ld4u(x1r, x2r, c + 4);
    }
#pragma unroll
    for (int i = 0; i < 4; ++i) {
        int tn = w * 4 + i;
        gload16(Wihp + ((tn * 18 + 0) << 9) + lane * 8, &Bb[0][tn][lane * 8]);
    }
#pragma unroll
    for (int i = 0; i < 4; ++i) {
        int tn = w * 4 + i;
        gload16(Wihp + ((tn * 18 + 1) << 9) + lane * 8, &Bb[1][tn][lane * 8]);
    }
    cvtw(P[0][0], P[0][1], &Ab[0][w][lane * 8]);   // auto-waits x(0)
    WAITV(4); LGKM0(); BAR(); MEMF();              // B(0) done; B(1) in flight

    // ---- iters 0..11: issue x(s+6) then B(s+2); WAITV(6) -> B(s+1) done ----
#pragma unroll
    for (int s = 0; s < 12; ++s) {
        {
            int c = (s + 6) * 32 + ac0;
            P[s % 6][0] = ld4u(x1r, x2r, c);       // slot (s+6)%6 == s%6
            P[s % 6][1] = ld4u(x1r, x2r, c + 4);
        }
#pragma unroll
        for (int i = 0; i < 4; ++i) {
            int tn = w * 4 + i;
            gload16(Wihp + ((tn * 18 + (s + 2)) << 9) + lane * 8,
                    &Bb[(s + 2) % 3][tn][lane * 8]);
        }
        k1_step(&Ab[s & 1][0][0], &Bb[s % 3][0][0], w, lane, acc);
        cvtw(P[(s + 1) % 6][0], P[(s + 1) % 6][1], &Ab[(s + 1) & 1][w][lane * 8]);
        WAITV(6); LGKM0(); BAR(); MEMF();
    }

    // ---- iters 12..15: x exhausted; WAITV(4) -> B(s+1) done ----
#pragma unroll
    for (int s = 12; s < 16; ++s) {
#pragma unroll
        for (int i = 0; i < 4; ++i) {
            int tn = w * 4 + i;
            gload16(Wihp + ((tn * 18 + (s + 2)) << 9) + lane * 8,
                    &Bb[(s + 2) % 3][tn][lane * 8]);
        }
        k1_step(&Ab[s & 1][0][0], &Bb[s % 3][0][0], w, lane, acc);
        cvtw(P[(s + 1) % 6][0], P[(s + 1) % 6][1], &Ab[(s + 1) & 1][w][lane * 8]);
        WAITV(4); LGKM0(); BAR(); MEMF();
    }

    // ---- iter 16: no issues; drain; iter 17 ----
    k1_step(&Ab[0][0][0], &Bb[1][0][0], w, lane, acc);     // 16&1=0, 16%3=1
    cvtw(P[5][0], P[5][1], &Ab[1][w][lane * 8]);           // x(17) in P[17%6=5]
    WAITV(0); LGKM0(); BAR(); MEMF();
    k1_step(&Ab[1][0][0], &Bb[2][0][0], w, lane, acc);     // 17&1=1, 17%3=2

    // ---- epilogue ----
#pragma unroll
    for (int nt = 0; nt < 4; ++nt) {
        float bv = biasg[w * 64 + nt * 16 + c16];
#pragma unroll
        for (int mt = 0; mt < 8; ++mt) {
            short4v o;
#pragma unroll
            for (int r = 0; r < 4; ++r) o[r] = f2bs(acc[mt][nt][r] + bv);
            int tm = (m0 >> 4) + mt, tn = w * 4 + nt;
            *(short4v*)&xg[((tm * 32 + tn) << 8) + lane * 4] = o;
        }
    }
}

// ---------------------------------------------------------------------------
// k2_rec: fused LSTM recurrence, 32 samples/block, 512 blocks, 512 thr.
// ---------------------------------------------------------------------------
__global__ __launch_bounds__(512, 2) void k2_rec(
    const short* __restrict__ Whhp, const short* __restrict__ xg,
    short* __restrict__ hs)
{
    __shared__ __align__(16) short hb[2][32][136];
    const int tid  = threadIdx.x;
    const int w    = tid >> 6;
    const int lane = tid & 63;
    const int quad = lane >> 4;
    const int c16  = lane & 15;
    const int btile = blockIdx.x * 2;       // sample-tile base (32 samples)

    short8 bfr[4][4];                       // [gate][ks]
#pragma unroll
    for (int g = 0; g < 4; ++g)
#pragma unroll
        for (int ks = 0; ks < 4; ++ks)
            bfr[g][ks] = *(const short8*)&Whhp[((((g * 8 + w) * 4) + ks) << 9) + lane * 8];

    float cst[2][4];
#pragma unroll
    for (int mt = 0; mt < 2; ++mt)
#pragma unroll
        for (int r = 0; r < 4; ++r) cst[mt][r] = 0.f;

    const int j = w * 16 + c16;

    for (int t = 0; t < TT; ++t) {
        short4v xq[2][4];
#pragma unroll
        for (int mt = 0; mt < 2; ++mt)
#pragma unroll
            for (int g = 0; g < 4; ++g)
                xq[mt][g] = *(const short4v*)
                    &xg[((((t << 10) + btile + mt) * 32 + (g * 8 + w)) << 8) + lane * 4];

        f32x4 acc[2][4];
#pragma unroll
        for (int mt = 0; mt < 2; ++mt)
#pragma unroll
            for (int g = 0; g < 4; ++g)
                acc[mt][g] = (f32x4){0.f, 0.f, 0.f, 0.f};

        if (t > 0) {
            const short (*cur)[136] = hb[(t - 1) & 1];
#pragma unroll
            for (int ks = 0; ks < 4; ++ks) {
                short8 a[2];
#pragma unroll
                for (int mt = 0; mt < 2; ++mt)
                    a[mt] = *(const short8*)&cur[mt * 16 + c16][ks * 32 + quad * 8];
#pragma unroll
                for (int mt = 0; mt < 2; ++mt)
#pragma unroll
                    for (int g = 0; g < 4; ++g)
                        acc[mt][g] = MFMA(a[mt], bfr[g][ks], acc[mt][g]);
            }
        }

        short (*nxt)[136] = hb[t & 1];
#pragma unroll
        for (int mt = 0; mt < 2; ++mt) {
#pragma unroll
            for (int r = 0; r < 4; ++r) {
                int m = mt * 16 + quad * 4 + r;
                float gi = acc[mt][0][r] + b2f(xq[mt][0][r]);
                float gf = acc[mt][1][r] + b2f(xq[mt][1][r]);
                float gg = acc[mt][2][r] + b2f(xq[mt][2][r]);
                float go = acc[mt][3][r] + b2f(xq[mt][3][r]);
                float cn = sigf(gf) * cst[mt][r] + sigf(gi) * mytanh(gg);
                cst[mt][r] = cn;
                nxt[m][j] = f2bs(sigf(go) * mytanh(cn));
            }
        }
        __syncthreads();
        {
            int tm = w >> 2, kt = w & 3;
            short8 v = *(const short8*)&nxt[tm * 16 + c16][kt * 32 + quad * 8];
            *(short8*)&hs[(((btile + tm) * 20 + t * 4 + kt) << 9) + lane * 8] = v;
        }
    }
}

// ---------------------------------------------------------------------------
// mlp: fused 640->576(531)->256->64->2 + softmax. 32 samples/block, 256 thr.
// ---------------------------------------------------------------------------
__global__ __launch_bounds__(256, 2) void mlp_kernel(
    const short* __restrict__ hs,
    const short* __restrict__ W1p, const float* __restrict__ b1p,
    const short* __restrict__ W2p, const float* __restrict__ b2,
    const short* __restrict__ W3p, const float* __restrict__ b3,
    const float* __restrict__ W4,  const float* __restrict__ b4,
    float* __restrict__ out)
{
    __shared__ __align__(16) short a1[32][584];
    __shared__ __align__(16) short a2[32][264];
    __shared__ __align__(16) short a3[32][72];
    const int tid  = threadIdx.x;
    const int w    = tid >> 6;
    const int lane = tid & 63;
    const int quad = lane >> 4;
    const int c16  = lane & 15;
    const int m0   = blockIdx.x * 32;
    const int mtile = blockIdx.x * 2;

    {
        f32x4 acc[2][9];
#pragma unroll
        for (int mt = 0; mt < 2; ++mt)
#pragma unroll
            for (int i = 0; i < 9; ++i)
                acc[mt][i] = (f32x4){0.f, 0.f, 0.f, 0.f};
#pragma unroll 4
        for (int ks = 0; ks < 20; ++ks) {
            short8 a[2];
#pragma unroll
            for (int mt = 0; mt < 2; ++mt)
                a[mt] = *(const short8*)&hs[(((mtile + mt) * 20 + ks) << 9) + lane * 8];
#pragma unroll
            for (int i = 0; i < 9; ++i) {
                short8 b = *(const short8*)&W1p[(((w * 9 + i) * 20 + ks) << 9) + lane * 8];
                acc[0][i] = MFMA(a[0], b, acc[0][i]);
                acc[1][i] = MFMA(a[1], b, acc[1][i]);
            }
        }
#pragma unroll
        for (int i = 0; i < 9; ++i) {
            int n = (w * 9 + i) * 16 + c16;
            float bv = b1p[n];
#pragma unroll
            for (int mt = 0; mt < 2; ++mt)
#pragma unroll
                for (int r = 0; r < 4; ++r) {
                    int m = mt * 16 + quad * 4 + r;
                    float v = acc[mt][i][r] + bv;
                    a1[m][n] = f2bs(v > 0.f ? v : 0.f);
                }
        }
    }
    __syncthreads();

    {
        f32x4 acc[2][4];
#pragma unroll
        for (int mt = 0; mt < 2; ++mt)
#pragma unroll
            for (int i = 0; i < 4; ++i)
                acc[mt][i] = (f32x4){0.f, 0.f, 0.f, 0.f};
#pragma unroll 4
        for (int ks = 0; ks < 17; ++ks) {
            short8 a[2];
#pragma unroll
            for (int mt = 0; mt < 2; ++mt)
                a[mt] = *(const short8*)&a1[mt * 16 + c16][ks * 32 + quad * 8];
#pragma unroll
            for (int i = 0; i < 4; ++i) {
                short8 b = *(const short8*)&W2p[(((w * 4 + i) * 17 + ks) << 9) + lane * 8];
                acc[0][i] = MFMA(a[0], b, acc[0][i]);
                acc[1][i] = MFMA(a[1], b, acc[1][i]);
            }
        }
#pragma unroll
        for (int i = 0; i < 4; ++i) {
            int n = (w * 4 + i) * 16 + c16;
            float bv = b2[n];
#pragma unroll
            for (int mt = 0; mt < 2; ++mt)
#pragma unroll
                for (int r = 0; r < 4; ++r) {
                    int m = mt * 16 + quad * 4 + r;
                    float v = acc[mt][i][r] + bv;
                    a2[m][n] = f2bs(v > 0.f ? v : 0.f);
                }
        }
    }
    __syncthreads();

    {
        f32x4 acc[2];
        acc[0] = (f32x4){0.f, 0.f, 0.f, 0.f};
        acc[1] = (f32x4){0.f, 0.f, 0.f, 0.f};
#pragma unroll
        for (int ks = 0; ks < 8; ++ks) {
            short8 a[2];
#pragma unroll
            for (int mt = 0; mt < 2; ++mt)
                a[mt] = *(const short8*)&a2[mt * 16 + c16][ks * 32 + quad * 8];
            short8 b = *(const short8*)&W3p[((w * 8 + ks) << 9) + lane * 8];
            acc[0] = MFMA(a[0], b, acc[0]);
            acc[1] = MFMA(a[1], b, acc[1]);
        }
        int n = w * 16 + c16;
        float bv = b3[n];
#pragma unroll
        for (int mt = 0; mt < 2; ++mt)
#pragma unroll
            for (int r = 0; r < 4; ++r) {
                int m = mt * 16 + quad * 4 + r;
                float v = acc[mt][r] + bv;
                a3[m][n] = f2bs(v > 0.f ? v : 0.f);
            }
    }
    __syncthreads();

    if (tid < 64) {
        int m   = tid >> 1;
        int cls = tid & 1;
        float s = b4[cls];
#pragma unroll 8
        for (int k = 0; k < 64; ++k)
            s += b2f(a3[m][k]) * W4[cls * 64 + k];
        float other = __shfl_xor(s, 1);
        float p = 1.f / (1.f + __expf(other - s));
        out[(m0 + m) * 2 + cls] = p;
    }
}

// ---------------------------------------------------------------------------
extern "C" void kernel_launch(void* const* d_in, const int* in_sizes, int n_in,
                              void* d_out, int out_size, void* d_ws, size_t ws_size,
                              hipStream_t stream)
{
    (void)in_sizes; (void)n_in; (void)out_size;
    if (ws_size < (size_t)WS_NEED) return;

    const float* x1   = (const float*)d_in[0];
    const float* x2   = (const float*)d_in[1];
    const float* W_ih = (const float*)d_in[2];
    const float* W_hh = (const float*)d_in[3];
    const float* b_ih = (const float*)d_in[4];
    const float* b_hh = (const float*)d_in[5];
    const float* W1   = (const float*)d_in[6];
    const float* b1   = (const float*)d_in[7];
    const float* W2   = (const float*)d_in[8];
    const float* b2   = (const float*)d_in[9];
    const float* W3   = (const float*)d_in[10];
    const float* b3   = (const float*)d_in[11];
    const float* W4   = (const float*)d_in[12];
    const float* b4   = (const float*)d_in[13];

    char* ws = (char*)d_ws;
    short* Wihp  = (short*)(ws + O_WIH);
    short* Whhp  = (short*)(ws + O_WHH);
    short* W1p   = (short*)(ws + O_W1);
    short* W2p   = (short*)(ws + O_W2);
    short* W3p   = (short*)(ws + O_W3);
    float* biasg = (float*)(ws + O_BG);
    float* b1p   = (float*)(ws + O_B1);
    short* xg    = (short*)(ws + O_XG);
    short* hsb   = (short*)(ws + O_HS);

    prep_kernel<<<3461, 256, 0, stream>>>(W_ih, W_hh, b_ih, b_hh, W1, b1, W2, W3,
                                          Wihp, Whhp, biasg, W1p, b1p, W2p, W3p);
    // A/B within-probe: control first, variant second (variant's xg wins).
    k1_xgemm<<<640, 512, 0, stream>>>(x1, x2, Wihp, biasg, xg);
    k1_deep <<<640, 512, 0, stream>>>(x1, x2, Wihp, biasg, xg);
    k2_rec<<<512, 512, 0, stream>>>(Whhp, xg, hsb);
    mlp_kernel<<<512, 256, 0, stream>>>(hsb, W1p, b1p, W2p, b2, W3p, b3, W4, b4,
                                        (float*)d_out);
}

// Round 4
// 486.302 us; speedup vs baseline: 1.2050x; 1.2050x over previous
//
#include <hip/hip_runtime.h>
#include <hip/hip_bf16.h>

// ---------------------------------------------------------------------------
// concat(x1,x2) -> LSTM(551->128, T=5) -> MLP 640->531->256->64->2 -> softmax
// B=16384, T=5, IN=551, H=128. bf16 MFMA 16x16x32, fp32 accum.
// R6: dataflow restructure.
//   packx: x fp32 -> Xp bf16 A-frag tiles (t-major), coalesced streaming.
//   fused: gate-GEMM (pure global_load_lds, counted-vmcnt half-step pipeline,
//          A staged 4 units ahead) + LSTM pointwise on live acc (xg never
//          materialized) + full MLP from LDS (hs never materialized).
//   64 samples/block, 256 blocks (1/CU), 512 thr. LDS 157 KB phase-union.
// Packed B/A-tile layout: 16(n|m) x 32(k) tile = 512 elems, element
//   (n,k) -> tile(tn=n>>4, tk=k>>5) at offset lane*8+j, lane=((k>>3)&3)*16+(n&15), j=k&7.
// C-frag: col=lane&15, row=(lane>>4)*4+r.
// ---------------------------------------------------------------------------

typedef short  short8  __attribute__((ext_vector_type(8)));
typedef short  short4v __attribute__((ext_vector_type(4)));
typedef float  f32x4   __attribute__((ext_vector_type(4)));

#define MFMA(a, b, c) __builtin_amdgcn_mfma_f32_16x16x32_bf16((a), (b), (c), 0, 0, 0)
#define WAITV(N) asm volatile("s_waitcnt vmcnt(" #N ")" ::: "memory")
#define MEMF()   asm volatile("" ::: "memory")
#define BAR()    __builtin_amdgcn_s_barrier()

__device__ __forceinline__ short f2bs(float f) {
    __hip_bfloat16 h = __float2bfloat16(f);   // RNE
    union { __hip_bfloat16 h; short s; } u; u.h = h; return u.s;
}
__device__ __forceinline__ float b2f(short s) {
    union { unsigned u; float f; } v; v.u = ((unsigned)(unsigned short)s) << 16; return v.f;
}
__device__ __forceinline__ float sigf(float x)  { return 1.f / (1.f + __expf(-x)); }
__device__ __forceinline__ float mytanh(float x){ return 2.f / (1.f + __expf(-2.f * x)) - 1.f; }

// async global(16B) -> LDS, lane-linear dest
__device__ __forceinline__ void gload16(const short* g, short* l) {
    __builtin_amdgcn_global_load_lds(
        (const __attribute__((address_space(1))) void*)g,
        (__attribute__((address_space(3))) void*)l, 16, 0, 0);
}

// ---------------- constants ----------------
#define BB     16384
#define TT     5
#define F1     300
#define F2     251
#define INF    551
#define KP     576          // padded K for input GEMM (18 k-tiles)
#define G4     512
#define HH     128
#define FLAT   640          // T*H (20 k-tiles)
#define L1N    531
#define L1P    576
#define L1KP   544          // 17 k-tiles
#define L2N    256
#define L3N    64

// ws offsets (bytes)
#define O_WIH  0u
#define O_WHH  589824u
#define O_W1   720896u
#define O_W2   1458176u
#define O_W3   1736704u
#define O_BG   1769472u
#define O_B1   1771520u
#define O_XP   1773824u
#define WS_NEED 96145664u   // O_XP + 5120*18*1024

// ---------------------------------------------------------------------------
// prep: weights fp32 -> bf16, packed in B-fragment tile order
// ---------------------------------------------------------------------------
__device__ __forceinline__ void pack_b(const float* __restrict__ W, short* __restrict__ dst,
                                       int i, int tpn, int Nsrc, int Ksrc, int ldw)
{
    int tile = i >> 9, rem = i & 511, lane = rem >> 3, jj = rem & 7;
    int tn = tile / tpn, tk = tile - tn * tpn;
    int n = tn * 16 + (lane & 15);
    int k = tk * 32 + (lane >> 4) * 8 + jj;
    float v = (n < Nsrc && k < Ksrc) ? W[n * ldw + k] : 0.f;
    dst[i] = f2bs(v);
}

__global__ void prep_kernel(
    const float* __restrict__ W_ih, const float* __restrict__ W_hh,
    const float* __restrict__ b_ih, const float* __restrict__ b_hh,
    const float* __restrict__ W1,   const float* __restrict__ b1,
    const float* __restrict__ W2,   const float* __restrict__ W3,
    short* __restrict__ Wihp, short* __restrict__ Whhp, float* __restrict__ biasg,
    short* __restrict__ W1p,  float* __restrict__ b1p,  short* __restrict__ W2p,
    short* __restrict__ W3p)
{
    const int N0 = G4 * KP;            // 294912
    const int N1 = N0 + G4 * HH;       // +65536
    const int N2 = N1 + L1P * FLAT;    // +368640
    const int N3 = N2 + L2N * L1KP;    // +139264
    const int N4 = N3 + L3N * L2N;     // +16384
    const int N5 = N4 + G4;
    const int N6 = N5 + L1P;
    const int stride = gridDim.x * blockDim.x;
    for (int i = blockIdx.x * blockDim.x + threadIdx.x; i < N6; i += stride) {
        if (i < N0)      pack_b(W_ih, Wihp, i,       18, G4,  INF, INF);
        else if (i < N1) pack_b(W_hh, Whhp, i - N0,   4, G4,  HH,  HH);
        else if (i < N2) pack_b(W1,   W1p,  i - N1,  20, L1N, FLAT, FLAT);
        else if (i < N3) pack_b(W2,   W2p,  i - N2,  17, L2N, L1N, L1N);
        else if (i < N4) pack_b(W3,   W3p,  i - N3,   8, L3N, L2N, L2N);
        else if (i < N5) { int j = i - N4; biasg[j] = b_ih[j] + b_hh[j]; }
        else             { int j = i - N5; b1p[j] = (j < L1N) ? b1[j] : 0.f; }
    }
}

// ---------------------------------------------------------------------------
// safe concat load: c<300 -> x1; 300..547 -> x2 float4; 548 straddle; >=551 -> 0
// ---------------------------------------------------------------------------
__device__ __forceinline__ float4 ld4u(const float* __restrict__ x1r,
                                       const float* __restrict__ x2r, int c)
{
    if (c + 3 < F1) return *(const float4*)(x1r + c);
    if (c + 3 < INF) return *(const float4*)(x2r + (c - F1));
    float4 r;
    r.x = (c + 0 < INF) ? x2r[c - F1 + 0] : 0.f;
    r.y = (c + 1 < INF) ? x2r[c - F1 + 1] : 0.f;
    r.z = (c + 2 < INF) ? x2r[c - F1 + 2] : 0.f;
    r.w = (c + 3 < INF) ? x2r[c - F1 + 3] : 0.f;
    return r;
}

// ---------------------------------------------------------------------------
// packx: x (fp32 rows) -> Xp (bf16 A-frag tiles), t-major row index t*B+b.
// Block = 16 rows of one t (1 m-tile). Phase1: coalesced row loads -> LDS
// row-major bf16. Phase2: frag-gather ds_read_b128 -> contiguous 16B stores.
// ---------------------------------------------------------------------------
__global__ __launch_bounds__(256, 4) void packx_kernel(
    const float* __restrict__ x1, const float* __restrict__ x2,
    short* __restrict__ Xp)
{
    __shared__ __align__(16) short At[16][584];
    const int tid  = threadIdx.x;
    const int w    = tid >> 6;
    const int lane = tid & 63;
    const int t    = blockIdx.x >> 10;
    const int bt   = blockIdx.x & 1023;
    const int b0   = bt << 4;

#pragma unroll
    for (int rr = 0; rr < 4; ++rr) {
        int row = w * 4 + rr;
        const float* x1r = x1 + ((size_t)(b0 + row) * TT + t) * F1;
        const float* x2r = x2 + ((size_t)(b0 + row) * TT + t) * F2;
#pragma unroll
        for (int p = 0; p < 3; ++p) {
            int c = p * 256 + lane * 4;
            if (c < 576) {
                float4 v = ld4u(x1r, x2r, c);   // >=551 zero-padded (finite)
                short4v s4;
                s4[0] = f2bs(v.x); s4[1] = f2bs(v.y);
                s4[2] = f2bs(v.z); s4[3] = f2bs(v.w);
                *(short4v*)&At[row][c] = s4;
            }
        }
    }
    __syncthreads();

    const int gm = (t << 10) + bt;       // global m-tile (t-major)
    for (int slot = tid; slot < 1152; slot += 256) {   // 18 tiles * 64 lanes
        int tk = slot >> 6, l = slot & 63;
        short8 v = *(const short8*)&At[l & 15][tk * 32 + ((l >> 4) & 3) * 8];
        *(short8*)&Xp[((gm * 18 + tk) << 9) + l * 8] = v;
    }
}

// ---------------------------------------------------------------------------
// fused: gate-GEMM + LSTM + MLP + softmax. 256 blocks x 512 thr, 64 samples.
// t-loop: 36 half-step units/t; unit u: B-half (16 tiles) staged 2 units
// ahead, A (4 tiles) staged 4 units ahead; counted WAITV(3/2), BAR; 8 MFMA.
// Wave w owns n-tiles {g*8+w}. Pointwise on live acc; h->hb; hs->hsL (LDS).
// MLP: 8 waves = 2 m-halves x 4 n-groups, layers from LDS union.
// ---------------------------------------------------------------------------
__global__ __launch_bounds__(512, 2) void fused_kernel(
    const short* __restrict__ Xp,  const short* __restrict__ Wihp,
    const short* __restrict__ Whhp, const float* __restrict__ biasg,
    const short* __restrict__ W1p, const float* __restrict__ b1p,
    const short* __restrict__ W2p, const float* __restrict__ b2,
    const short* __restrict__ W3p, const float* __restrict__ b3,
    const float* __restrict__ W4,  const float* __restrict__ b4,
    float* __restrict__ out)
{
    // LDS union (160768 B):
    //  region0 (0..81920):      hsL [80][512] bf16   | a2 [64][264]
    //  region1 (81920..160768): SA[3][4][512] + SB[3][16][512] + hb[64][136]
    //                           | a1 [64][584] | a3 [64][72]
    __shared__ __align__(16) char smem[160768];
    short*  hsL = (short*)smem;
    short (*a2)[264] = (short (*)[264])smem;
    char* R1 = smem + 81920;
    short (*SA)[4][512]  = (short (*)[4][512])R1;
    short (*SB)[16][512] = (short (*)[16][512])(R1 + 12288);
    short (*hb)[136]     = (short (*)[136])(R1 + 61440);
    short (*a1)[584]     = (short (*)[584])R1;
    short (*a3)[72]      = (short (*)[72])R1;

    const int tid  = threadIdx.x;
    const int w    = tid >> 6;
    const int lane = tid & 63;
    const int quad = lane >> 4;
    const int c16  = lane & 15;
    const int b0   = blockIdx.x * 64;
    const int tmb  = blockIdx.x * 4;

    // W_hh B-fragments in registers (reused all t)
    short8 bfr[4][4];
#pragma unroll
    for (int g = 0; g < 4; ++g)
#pragma unroll
        for (int ks = 0; ks < 4; ++ks)
            bfr[g][ks] = *(const short8*)&Whhp[((((g * 8 + w) * 4) + ks) << 9) + lane * 8];
    float bv[4];
#pragma unroll
    for (int g = 0; g < 4; ++g) bv[g] = biasg[((g * 8 + w) << 4) + c16];

    float cst[4][4];
#pragma unroll
    for (int mt = 0; mt < 4; ++mt)
#pragma unroll
        for (int r = 0; r < 4; ++r) cst[mt][r] = 0.f;

    for (int t = 0; t < TT; ++t) {
        f32x4 acc[4][4];
#pragma unroll
        for (int mt = 0; mt < 4; ++mt)
#pragma unroll
            for (int g = 0; g < 4; ++g)
                acc[mt][g] = (f32x4){0.f, 0.f, 0.f, 0.f};

        auto stageB = [&](int u) {            // u compile-time in unrolled ctx
            const int tk = u >> 1, p = u & 1;
#pragma unroll
            for (int gg = 0; gg < 2; ++gg) {
                int tn = (2 * p + gg) * 8 + w;
                gload16(Wihp + ((tn * 18 + tk) << 9) + lane * 8,
                        &SB[u % 3][gg * 8 + w][lane * 8]);
            }
        };
        auto stageA = [&](int s) {            // wave w stages m-tile w (w<4)
            gload16(Xp + ((((t << 10) + tmb + w) * 18 + s) << 9) + lane * 8,
                    &SA[s % 3][w][lane * 8]);
        };

        // ---- prologue: B(0), A(0), A(1), B(1); overlap h-MFMA; wait; bar ----
        stageB(0);
        if (w < 4) { stageA(0); stageA(1); }
        stageB(1);
        if (t > 0) {
#pragma unroll
            for (int ks = 0; ks < 4; ++ks) {
                short8 ah[4];
#pragma unroll
                for (int mt = 0; mt < 4; ++mt)
                    ah[mt] = *(const short8*)&hb[mt * 16 + c16][ks * 32 + quad * 8];
#pragma unroll
                for (int g = 0; g < 4; ++g)
#pragma unroll
                    for (int mt = 0; mt < 4; ++mt)
                        acc[mt][g] = MFMA(ah[mt], bfr[g][ks], acc[mt][g]);
            }
        }
        if (w < 4) { WAITV(3); } else { WAITV(2); }
        BAR(); MEMF();

        // ---- main: units 0..31 (16 double-iters) ----
#pragma unroll
        for (int v = 0; v < 32; v += 2) {
            // even unit v: stage B(v+2) + A(v/2+2); MFMA g{0,1}
            stageB(v + 2);
            if (w < 4) stageA(v / 2 + 2);
            short8 a[4];
#pragma unroll
            for (int mt = 0; mt < 4; ++mt)
                a[mt] = *(const short8*)&SA[(v >> 1) % 3][mt][lane * 8];
#pragma unroll
            for (int gg = 0; gg < 2; ++gg) {
                short8 b = *(const short8*)&SB[v % 3][gg * 8 + w][lane * 8];
#pragma unroll
                for (int mt = 0; mt < 4; ++mt)
                    acc[mt][gg] = MFMA(a[mt], b, acc[mt][gg]);
            }
            if (w < 4) { WAITV(3); } else { WAITV(2); }
            BAR(); MEMF();
            // odd unit v+1: stage B(v+3); MFMA g{2,3} (same A)
            stageB(v + 3);
#pragma unroll
            for (int gg = 0; gg < 2; ++gg) {
                short8 b = *(const short8*)&SB[(v + 1) % 3][gg * 8 + w][lane * 8];
#pragma unroll
                for (int mt = 0; mt < 4; ++mt)
                    acc[mt][2 + gg] = MFMA(a[mt], b, acc[mt][2 + gg]);
            }
            WAITV(2);
            BAR(); MEMF();
        }
        // ---- epilogue units 32..35 ----
        {
            stageB(34);
            short8 a[4];
#pragma unroll
            for (int mt = 0; mt < 4; ++mt)
                a[mt] = *(const short8*)&SA[1][mt][lane * 8];       // step16 %3
#pragma unroll
            for (int gg = 0; gg < 2; ++gg) {
                short8 b = *(const short8*)&SB[2][gg * 8 + w][lane * 8]; // 32%3
#pragma unroll
                for (int mt = 0; mt < 4; ++mt)
                    acc[mt][gg] = MFMA(a[mt], b, acc[mt][gg]);
            }
            WAITV(2); BAR(); MEMF();
            stageB(35);
#pragma unroll
            for (int gg = 0; gg < 2; ++gg) {
                short8 b = *(const short8*)&SB[0][gg * 8 + w][lane * 8]; // 33%3
#pragma unroll
                for (int mt = 0; mt < 4; ++mt)
                    acc[mt][2 + gg] = MFMA(a[mt], b, acc[mt][2 + gg]);
            }
            WAITV(2); BAR(); MEMF();
            short8 a7[4];
#pragma unroll
            for (int mt = 0; mt < 4; ++mt)
                a7[mt] = *(const short8*)&SA[2][mt][lane * 8];      // step17 %3
#pragma unroll
            for (int gg = 0; gg < 2; ++gg) {
                short8 b = *(const short8*)&SB[1][gg * 8 + w][lane * 8]; // 34%3
#pragma unroll
                for (int mt = 0; mt < 4; ++mt)
                    acc[mt][gg] = MFMA(a7[mt], b, acc[mt][gg]);
            }
            WAITV(0); BAR(); MEMF();
#pragma unroll
            for (int gg = 0; gg < 2; ++gg) {
                short8 b = *(const short8*)&SB[2][gg * 8 + w][lane * 8]; // 35%3
#pragma unroll
                for (int mt = 0; mt < 4; ++mt)
                    acc[mt][2 + gg] = MFMA(a7[mt], b, acc[mt][2 + gg]);
            }
        }
        // ---- LSTM pointwise on live acc; h -> hb ----
#pragma unroll
        for (int mt = 0; mt < 4; ++mt)
#pragma unroll
            for (int r = 0; r < 4; ++r) {
                int m = mt * 16 + quad * 4 + r;
                float gi = acc[mt][0][r] + bv[0];
                float gf = acc[mt][1][r] + bv[1];
                float gq = acc[mt][2][r] + bv[2];
                float go = acc[mt][3][r] + bv[3];
                float cn = sigf(gf) * cst[mt][r] + sigf(gi) * mytanh(gq);
                cst[mt][r] = cn;
                hb[m][w * 16 + c16] = f2bs(sigf(go) * mytanh(cn));
            }
        __syncthreads();
        // ---- export h_t -> hsL (A-frag layout) ----
#pragma unroll
        for (int i = 0; i < 2; ++i) {
            int slot = w + 8 * i, tm = slot >> 2, kt = slot & 3;
            short8 hv = *(const short8*)&hb[tm * 16 + c16][kt * 32 + quad * 8];
            *(short8*)&hsL[((tm * 20 + (t << 2) + kt) << 9) + lane * 8] = hv;
        }
        __syncthreads();
    }

    // ---- MLP: 8 waves = 2 m-halves (mh) x 4 n-groups (wn) ----
    const int mh = w >> 2, wn = w & 3;
    // layer 1: K=640 (20 ks), N=576: wn -> 9 n-tiles
    {
        f32x4 acc[2][9];
#pragma unroll
        for (int mt = 0; mt < 2; ++mt)
#pragma unroll
            for (int i = 0; i < 9; ++i) acc[mt][i] = (f32x4){0.f, 0.f, 0.f, 0.f};
#pragma unroll 4
        for (int ks = 0; ks < 20; ++ks) {
            short8 a[2];
#pragma unroll
            for (int mt = 0; mt < 2; ++mt)
                a[mt] = *(const short8*)&hsL[(((mh * 2 + mt) * 20 + ks) << 9) + lane * 8];
#pragma unroll
            for (int i = 0; i < 9; ++i) {
                short8 b = *(const short8*)&W1p[(((wn * 9 + i) * 20 + ks) << 9) + lane * 8];
                acc[0][i] = MFMA(a[0], b, acc[0][i]);
                acc[1][i] = MFMA(a[1], b, acc[1][i]);
            }
        }
        // a1 (region1) does not alias hsL (region0): safe to write now
#pragma unroll
        for (int i = 0; i < 9; ++i) {
            int n = (wn * 9 + i) * 16 + c16;
            float bb = b1p[n];
#pragma unroll
            for (int mt = 0; mt < 2; ++mt)
#pragma unroll
                for (int r = 0; r < 4; ++r) {
                    int m = (mh * 2 + mt) * 16 + quad * 4 + r;
                    float vv = acc[mt][i][r] + bb;
                    a1[m][n] = f2bs(vv > 0.f ? vv : 0.f);
                }
        }
    }
    __syncthreads();
    // layer 2: K=544 (17 ks), N=256: wn -> 4 n-tiles (a2 overlays hsL: dead)
    {
        f32x4 acc[2][4];
#pragma unroll
        for (int mt = 0; mt < 2; ++mt)
#pragma unroll
            for (int i = 0; i < 4; ++i) acc[mt][i] = (f32x4){0.f, 0.f, 0.f, 0.f};
#pragma unroll 4
        for (int ks = 0; ks < 17; ++ks) {
            short8 a[2];
#pragma unroll
            for (int mt = 0; mt < 2; ++mt)
                a[mt] = *(const short8*)&a1[(mh * 2 + mt) * 16 + c16][ks * 32 + quad * 8];
#pragma unroll
            for (int i = 0; i < 4; ++i) {
                short8 b = *(const short8*)&W2p[(((wn * 4 + i) * 17 + ks) << 9) + lane * 8];
                acc[0][i] = MFMA(a[0], b, acc[0][i]);
                acc[1][i] = MFMA(a[1], b, acc[1][i]);
            }
        }
        __syncthreads();   // all a1 reads done before a2 write (a2 != a1 regions, but keep order strict)
#pragma unroll
        for (int i = 0; i < 4; ++i) {
            int n = (wn * 4 + i) * 16 + c16;
            float bb = b2[n];
#pragma unroll
            for (int mt = 0; mt < 2; ++mt)
#pragma unroll
                for (int r = 0; r < 4; ++r) {
                    int m = (mh * 2 + mt) * 16 + quad * 4 + r;
                    float vv = acc[mt][i][r] + bb;
                    a2[m][n] = f2bs(vv > 0.f ? vv : 0.f);
                }
        }
    }
    __syncthreads();
    // layer 3: K=256 (8 ks), N=64: wn -> 1 n-tile (a3 overlays a1: dead)
    {
        f32x4 acc[2];
        acc[0] = (f32x4){0.f, 0.f, 0.f, 0.f};
        acc[1] = (f32x4){0.f, 0.f, 0.f, 0.f};
#pragma unroll
        for (int ks = 0; ks < 8; ++ks) {
            short8 a[2];
#pragma unroll
            for (int mt = 0; mt < 2; ++mt)
                a[mt] = *(const short8*)&a2[(mh * 2 + mt) * 16 + c16][ks * 32 + quad * 8];
            short8 b = *(const short8*)&W3p[((wn * 8 + ks) << 9) + lane * 8];
            acc[0] = MFMA(a[0], b, acc[0]);
            acc[1] = MFMA(a[1], b, acc[1]);
        }
        __syncthreads();   // a2 reads done before a3 write (a3 overlays a1 region)
        int n = wn * 16 + c16;
        float bb = b3[n];
#pragma unroll
        for (int mt = 0; mt < 2; ++mt)
#pragma unroll
            for (int r = 0; r < 4; ++r) {
                int m = (mh * 2 + mt) * 16 + quad * 4 + r;
                float vv = acc[mt][r] + bb;
                a3[m][n] = f2bs(vv > 0.f ? vv : 0.f);
            }
    }
    __syncthreads();
    // layer 4 + softmax
    if (tid < 128) {
        int m = tid >> 1, cls = tid & 1;
        float s = b4[cls];
#pragma unroll 8
        for (int k = 0; k < 64; ++k)
            s += b2f(a3[m][k]) * W4[cls * 64 + k];
        float other = __shfl_xor(s, 1);
        out[(b0 + m) * 2 + cls] = 1.f / (1.f + __expf(other - s));
    }
}

// ---------------------------------------------------------------------------
extern "C" void kernel_launch(void* const* d_in, const int* in_sizes, int n_in,
                              void* d_out, int out_size, void* d_ws, size_t ws_size,
                              hipStream_t stream)
{
    (void)in_sizes; (void)n_in; (void)out_size;
    if (ws_size < (size_t)WS_NEED) return;

    const float* x1   = (const float*)d_in[0];
    const float* x2   = (const float*)d_in[1];
    const float* W_ih = (const float*)d_in[2];
    const float* W_hh = (const float*)d_in[3];
    const float* b_ih = (const float*)d_in[4];
    const float* b_hh = (const float*)d_in[5];
    const float* W1   = (const float*)d_in[6];
    const float* b1   = (const float*)d_in[7];
    const float* W2   = (const float*)d_in[8];
    const float* b2   = (const float*)d_in[9];
    const float* W3   = (const float*)d_in[10];
    const float* b3   = (const float*)d_in[11];
    const float* W4   = (const float*)d_in[12];
    const float* b4   = (const float*)d_in[13];

    char* ws = (char*)d_ws;
    short* Wihp  = (short*)(ws + O_WIH);
    short* Whhp  = (short*)(ws + O_WHH);
    short* W1p   = (short*)(ws + O_W1);
    short* W2p   = (short*)(ws + O_W2);
    short* W3p   = (short*)(ws + O_W3);
    float* biasg = (float*)(ws + O_BG);
    float* b1p   = (float*)(ws + O_B1);
    short* Xp    = (short*)(ws + O_XP);

    prep_kernel<<<3461, 256, 0, stream>>>(W_ih, W_hh, b_ih, b_hh, W1, b1, W2, W3,
                                          Wihp, Whhp, biasg, W1p, b1p, W2p, W3p);
    packx_kernel<<<5120, 256, 0, stream>>>(x1, x2, Xp);
    fused_kernel<<<256, 512, 0, stream>>>(Xp, Wihp, Whhp, biasg,
                                          W1p, b1p, W2p, b2, W3p, b3, W4, b4,
                                          (float*)d_out);
}

// Round 6
// 398.921 us; speedup vs baseline: 1.4690x; 1.2190x over previous
//
#include <hip/hip_runtime.h>
#include <hip/hip_bf16.h>

// ---------------------------------------------------------------------------
// concat(x1,x2) -> LSTM(551->128, T=5) -> MLP 640->531->256->64->2 -> softmax
// B=16384, T=5, IN=551, H=128. bf16 MFMA 16x16x32, fp32 accum.
// R8: R7 (m97-structure GEMM) with the A-staging path fixed:
//     - A staged via registers (4x float4/thread, per-lane x1/x2 select,
//       legal for 4B-aligned x2 rows), cvt fp32->bf16 ONCE at staging,
//       2x ds_write_b128 into bf16 As[128][32] with chunk-XOR swizzle
//       slot = ch ^ ((row>>1)&3)  (write & read both 2-way = free, m136).
//     - B staged via global_load_lds (16B-aligned packed W tiles).
//     - lgkmcnt(0) added before mid-step barrier (ds_write visibility).
//     - R7's unaligned global_load_lds from x2 (suspected fatal fault) gone.
//     BM=128 BN=128 BK=32, 256 thr, 16 KB LDS, vmcnt(0)+2 barriers per step,
//     XCD-swizzled grid (4 n-blocks of an m-panel share an XCD L2).
//     Concat tail: step 17 chunk 548 loads x2+247 (in-bounds), W_ih packed
//     with col547->0, cols548..551<-547..550 (exact algebra). k2/mlp = R0.
// Packed B/A-tile layout: 16(n|m) x 32(k) tile = 512 elems, element
//   (n,k) -> tile(tn=n>>4, tk=k>>5) at offset lane*8+j, lane=((k>>3)&3)*16+(n&15), j=k&7.
// Packed C-tile layout: 16x16 tile = 256 elems, (m,n) -> offset lane*4+r,
//   lane=((m>>2)&3)*16+(n&15), r=m&3.
// ---------------------------------------------------------------------------

typedef short  short8  __attribute__((ext_vector_type(8)));
typedef short  short4v __attribute__((ext_vector_type(4)));
typedef float  f32x4   __attribute__((ext_vector_type(4)));

#define MFMA(a, b, c) __builtin_amdgcn_mfma_f32_16x16x32_bf16((a), (b), (c), 0, 0, 0)
#define WAITV(N) asm volatile("s_waitcnt vmcnt(" #N ")" ::: "memory")
#define LGKM0()  asm volatile("s_waitcnt lgkmcnt(0)" ::: "memory")
#define MEMF()   asm volatile("" ::: "memory")
#define BAR()    __builtin_amdgcn_s_barrier()

__device__ __forceinline__ short f2bs(float f) {
    __hip_bfloat16 h = __float2bfloat16(f);   // RNE
    union { __hip_bfloat16 h; short s; } u; u.h = h; return u.s;
}
__device__ __forceinline__ float b2f(short s) {
    union { unsigned u; float f; } v; v.u = ((unsigned)(unsigned short)s) << 16; return v.f;
}
__device__ __forceinline__ float sigf(float x)  { return 1.f / (1.f + __expf(-x)); }
__device__ __forceinline__ float mytanh(float x){ return 2.f / (1.f + __expf(-2.f * x)) - 1.f; }

// async global(16B) -> LDS; dest is wave-uniform base, HW adds lane*16
__device__ __forceinline__ void gload16(const void* g, void* l) {
    __builtin_amdgcn_global_load_lds(
        (const __attribute__((address_space(1))) void*)g,
        (__attribute__((address_space(3))) void*)l, 16, 0, 0);
}

// ---------------- constants ----------------
#define BB     16384
#define TT     5
#define F1     300
#define F2     251
#define INF    551
#define KP     576          // padded K for input GEMM (18 k-tiles)
#define G4     512
#define HH     128
#define FLAT   640          // T*H (20 k-tiles)
#define L1N    531
#define L1P    576
#define L1KP   544          // 17 k-tiles
#define L2N    256
#define L3N    64

// ws offsets (bytes)
#define O_WIH  0u
#define O_WHH  589824u
#define O_W1   720896u
#define O_W2   1458176u
#define O_W3   1736704u
#define O_BG   1769472u
#define O_B1   1771520u
#define O_XG   1773824u
#define O_HS   85659904u
#define WS_NEED 106631424u

// ---------------------------------------------------------------------------
// prep: weights fp32 -> bf16, packed in B-fragment tile order.
// W_ih gets the shift-compensation: col547->0, cols 548..551 <- 547..550.
// ---------------------------------------------------------------------------
__device__ __forceinline__ void pack_b(const float* __restrict__ W, short* __restrict__ dst,
                                       int i, int tpn, int Nsrc, int Ksrc, int ldw)
{
    int tile = i >> 9, rem = i & 511, lane = rem >> 3, jj = rem & 7;
    int tn = tile / tpn, tk = tile - tn * tpn;
    int n = tn * 16 + (lane & 15);
    int k = tk * 32 + (lane >> 4) * 8 + jj;
    float v = (n < Nsrc && k < Ksrc) ? W[n * ldw + k] : 0.f;
    dst[i] = f2bs(v);
}

__device__ __forceinline__ void pack_bih(const float* __restrict__ W, short* __restrict__ dst,
                                         int i)
{
    int tile = i >> 9, rem = i & 511, lane = rem >> 3, jj = rem & 7;
    int tn = tile / 18, tk = tile - tn * 18;
    int n = tn * 16 + (lane & 15);
    int k = tk * 32 + (lane >> 4) * 8 + jj;
    // shift-compensated keff: k<=546 -> k; 547 -> dead; 548..551 -> k-1; >=552 dead
    int keff = (k <= 546) ? k : (k >= 548 && k <= 551) ? (k - 1) : -1;
    float v = (keff >= 0) ? W[n * INF + keff] : 0.f;
    dst[i] = f2bs(v);
}

__global__ void prep_kernel(
    const float* __restrict__ W_ih, const float* __restrict__ W_hh,
    const float* __restrict__ b_ih, const float* __restrict__ b_hh,
    const float* __restrict__ W1,   const float* __restrict__ b1,
    const float* __restrict__ W2,   const float* __restrict__ W3,
    short* __restrict__ Wihp, short* __restrict__ Whhp, float* __restrict__ biasg,
    short* __restrict__ W1p,  float* __restrict__ b1p,  short* __restrict__ W2p,
    short* __restrict__ W3p)
{
    const int N0 = G4 * KP;            // 294912
    const int N1 = N0 + G4 * HH;       // +65536
    const int N2 = N1 + L1P * FLAT;    // +368640
    const int N3 = N2 + L2N * L1KP;    // +139264
    const int N4 = N3 + L3N * L2N;     // +16384
    const int N5 = N4 + G4;
    const int N6 = N5 + L1P;
    const int stride = gridDim.x * blockDim.x;
    for (int i = blockIdx.x * blockDim.x + threadIdx.x; i < N6; i += stride) {
        if (i < N0)      pack_bih(W_ih, Wihp, i);
        else if (i < N1) pack_b(W_hh, Whhp, i - N0,   4, G4,  HH,  HH);
        else if (i < N2) pack_b(W1,   W1p,  i - N1,  20, L1N, FLAT, FLAT);
        else if (i < N3) pack_b(W2,   W2p,  i - N2,  17, L2N, L1N, L1N);
        else if (i < N4) pack_b(W3,   W3p,  i - N3,   8, L3N, L2N, L2N);
        else if (i < N5) { int j = i - N4; biasg[j] = b_ih[j] + b_hh[j]; }
        else             { int j = i - N5; b1p[j] = (j < L1N) ? b1[j] : 0.f; }
    }
}

// ---------------------------------------------------------------------------
// per-float4 concat select (4B-aligned-safe; boundary 300 is 4-aligned so
// no float4 straddles x1/x2). Valid for c <= 544.
// ---------------------------------------------------------------------------
__device__ __forceinline__ float4 ld4r(const float* __restrict__ x1r,
                                       const float* __restrict__ x2r, int c)
{
    const float* p = (c < F1) ? (x1r + c) : (x2r + (c - F1));
    return *(const float4*)p;
}

// ---------------------------------------------------------------------------
// k1_xgemm: xg = concat(x)@W_ih^T + bias.  m97 structure, reg-staged A.
// Grid 2560 = 640 m-panels x 4 n-blocks(gates), XCD-swizzled:
//   xcd = id&7, j = id>>3; m-panel = xcd*80 + j/4, nb = j&3.
// Block: 256 thr (4 waves, wave (wm,wn) = 2x2), BM=128 BN=128 BK=32.
// Per K-step: BAR; stage B (gload16) + A (regs->cvt->ds_write, swizzled);
// WAITV(0); LGKM0; BAR; ds_read frags; 16 MFMA/wave.
// ---------------------------------------------------------------------------
__global__ __launch_bounds__(256, 3) void k1_xgemm(
    const float* __restrict__ x1, const float* __restrict__ x2,
    const short* __restrict__ Wihp, const float* __restrict__ biasg,
    short* __restrict__ xg)
{
    __shared__ __align__(16) short As[128][32];   // 8 KB bf16, chunk-swizzled
    __shared__ __align__(16) short Bs[8][512];    // 8 KB packed B tiles
    const int tid  = threadIdx.x;
    const int w    = tid >> 6;
    const int lane = tid & 63;
    const int c16  = lane & 15;
    const int kq   = lane >> 4;          // 0..3 (A chunk to read)
    const int wm   = w >> 1, wn = w & 1;

    // XCD-swizzled mapping
    const int id  = blockIdx.x;
    const int mp  = (id & 7) * 80 + ((id >> 3) >> 2);   // m-panel 0..639
    const int nb  = (id >> 3) & 3;                      // gate / n-block
    const int m0  = mp * 128;
    const int t   = m0 >> 14;
    const int bb  = m0 & 16383;

    // A staging: thread -> row sr = tid>>1, half sh = tid&1 (cols 16sh..16sh+15)
    const int sr = tid >> 1, sh = tid & 1;
    const int arow = bb + sr;
    const float* x1r = x1 + ((size_t)arow * TT + t) * F1;
    const float* x2r = x2 + ((size_t)arow * TT + t) * F2;
    const int fA = (sr >> 1) & 3;                       // row swizzle field
    short* d0 = &As[sr][(((sh << 1)    ) ^ fA) << 3];   // chunk 2sh
    short* d1 = &As[sr][(((sh << 1) | 1) ^ fA) << 3];   // chunk 2sh+1

    f32x4 acc[4][4];
#pragma unroll
    for (int mt = 0; mt < 4; ++mt)
#pragma unroll
        for (int nt = 0; nt < 4; ++nt)
            acc[mt][nt] = (f32x4){0.f, 0.f, 0.f, 0.f};

    for (int s = 0; s < 18; ++s) {
        BAR(); MEMF();                   // previous step's LDS reads retired
        // ---- stage B (async, aligned) ----
#pragma unroll
        for (int i2 = 0; i2 < 2; ++i2) {
            int tnl = w * 2 + i2;        // 0..7
            gload16(Wihp + (((nb * 8 + tnl) * 18 + s) << 9) + lane * 8,
                    &Bs[tnl][0]);
        }
        // ---- stage A (regs -> cvt -> swizzled ds_write) ----
        float4 q0, q1, q2, q3;
        if (s < 17) {
            int c0 = s * 32 + sh * 16;   // <= 528; q3 at c0+12 <= 540
            q0 = ld4r(x1r, x2r, c0);
            q1 = ld4r(x1r, x2r, c0 + 4);
            q2 = ld4r(x1r, x2r, c0 + 8);
            q3 = ld4r(x1r, x2r, c0 + 12);
        } else {
            if (sh == 0) {
                q0 = *(const float4*)(x2r + 244);   // cols 544..547
                q1 = *(const float4*)(x2r + 247);   // x[547..550] -> k 548..551 (W shifted)
            } else {
                q0 = (float4){0.f, 0.f, 0.f, 0.f};
                q1 = q0;
            }
            q2 = (float4){0.f, 0.f, 0.f, 0.f};      // k >= 552: W = 0
            q3 = q2;
        }
        {
            short8 v0, v1;
            v0[0] = f2bs(q0.x); v0[1] = f2bs(q0.y); v0[2] = f2bs(q0.z); v0[3] = f2bs(q0.w);
            v0[4] = f2bs(q1.x); v0[5] = f2bs(q1.y); v0[6] = f2bs(q1.z); v0[7] = f2bs(q1.w);
            v1[0] = f2bs(q2.x); v1[1] = f2bs(q2.y); v1[2] = f2bs(q2.z); v1[3] = f2bs(q2.w);
            v1[4] = f2bs(q3.x); v1[5] = f2bs(q3.y); v1[6] = f2bs(q3.z); v1[7] = f2bs(q3.w);
            *(short8*)d0 = v0;
            *(short8*)d1 = v1;
        }
        WAITV(0); LGKM0(); BAR(); MEMF();

        // ---- compute: A frags (swizzled ds_read), 16 MFMA/wave ----
        short8 a[4];
#pragma unroll
        for (int mt = 0; mt < 4; ++mt) {
            int r = (wm * 4 + mt) * 16 + c16;
            a[mt] = *(const short8*)&As[r][(kq ^ ((r >> 1) & 3)) << 3];
        }
#pragma unroll
        for (int nt = 0; nt < 4; ++nt) {
            short8 b = *(const short8*)&Bs[wn * 4 + nt][lane * 8];
#pragma unroll
            for (int mt = 0; mt < 4; ++mt)
                acc[mt][nt] = MFMA(a[mt], b, acc[mt][nt]);
        }
    }

    // epilogue: +bias, packed C-tile store (8B/lane, coalesced)
#pragma unroll
    for (int nt = 0; nt < 4; ++nt) {
        int tn = nb * 8 + wn * 4 + nt;
        float bv = biasg[tn * 16 + c16];
#pragma unroll
        for (int mt = 0; mt < 4; ++mt) {
            short4v o;
#pragma unroll
            for (int r = 0; r < 4; ++r) o[r] = f2bs(acc[mt][nt][r] + bv);
            int tm = (m0 >> 4) + wm * 4 + mt;
            *(short4v*)&xg[((tm * 32 + tn) << 8) + lane * 4] = o;
        }
    }
}

// ---------------------------------------------------------------------------
// k2_rec: fused LSTM recurrence, 32 samples/block, 512 blocks, 512 thr.
// W_hh B-frags in registers (reused all t). xg read as packed C-tiles (8B/lane).
// h round-trips through LDS; hs exported in packed A-tile layout (16B/lane).
// ---------------------------------------------------------------------------
__global__ __launch_bounds__(512, 2) void k2_rec(
    const short* __restrict__ Whhp, const short* __restrict__ xg,
    short* __restrict__ hs)
{
    __shared__ __align__(16) short hb[2][32][136];
    const int tid  = threadIdx.x;
    const int w    = tid >> 6;
    const int lane = tid & 63;
    const int quad = lane >> 4;
    const int c16  = lane & 15;
    const int btile = blockIdx.x * 2;       // sample-tile base (32 samples)

    short8 bfr[4][4];                       // [gate][ks]
#pragma unroll
    for (int g = 0; g < 4; ++g)
#pragma unroll
        for (int ks = 0; ks < 4; ++ks)
            bfr[g][ks] = *(const short8*)&Whhp[((((g * 8 + w) * 4) + ks) << 9) + lane * 8];

    float cst[2][4];
#pragma unroll
    for (int mt = 0; mt < 2; ++mt)
#pragma unroll
        for (int r = 0; r < 4; ++r) cst[mt][r] = 0.f;

    const int j = w * 16 + c16;

    for (int t = 0; t < TT; ++t) {
        short4v xq[2][4];
#pragma unroll
        for (int mt = 0; mt < 2; ++mt)
#pragma unroll
            for (int g = 0; g < 4; ++g)
                xq[mt][g] = *(const short4v*)
                    &xg[((((t << 10) + btile + mt) * 32 + (g * 8 + w)) << 8) + lane * 4];

        f32x4 acc[2][4];
#pragma unroll
        for (int mt = 0; mt < 2; ++mt)
#pragma unroll
            for (int g = 0; g < 4; ++g)
                acc[mt][g] = (f32x4){0.f, 0.f, 0.f, 0.f};

        if (t > 0) {
            const short (*cur)[136] = hb[(t - 1) & 1];
#pragma unroll
            for (int ks = 0; ks < 4; ++ks) {
                short8 a[2];
#pragma unroll
                for (int mt = 0; mt < 2; ++mt)
                    a[mt] = *(const short8*)&cur[mt * 16 + c16][ks * 32 + quad * 8];
#pragma unroll
                for (int mt = 0; mt < 2; ++mt)
#pragma unroll
                    for (int g = 0; g < 4; ++g)
                        acc[mt][g] = MFMA(a[mt], bfr[g][ks], acc[mt][g]);
            }
        }

        short (*nxt)[136] = hb[t & 1];
#pragma unroll
        for (int mt = 0; mt < 2; ++mt) {
#pragma unroll
            for (int r = 0; r < 4; ++r) {
                int m = mt * 16 + quad * 4 + r;
                float gi = acc[mt][0][r] + b2f(xq[mt][0][r]);
                float gf = acc[mt][1][r] + b2f(xq[mt][1][r]);
                float gg = acc[mt][2][r] + b2f(xq[mt][2][r]);
                float go = acc[mt][3][r] + b2f(xq[mt][3][r]);
                float cn = sigf(gf) * cst[mt][r] + sigf(gi) * mytanh(gg);
                cst[mt][r] = cn;
                nxt[m][j] = f2bs(sigf(go) * mytanh(cn));
            }
        }
        __syncthreads();
        {
            int tm = w >> 2, kt = w & 3;
            short8 v = *(const short8*)&nxt[tm * 16 + c16][kt * 32 + quad * 8];
            *(short8*)&hs[(((btile + tm) * 20 + t * 4 + kt) << 9) + lane * 8] = v;
        }
    }
}

// ---------------------------------------------------------------------------
// mlp: fused 640->576(531)->256->64->2 + softmax. 32 samples/block, 256 thr.
// hs read as packed A-tiles; weights as packed B-tiles (all 16B/lane).
// ---------------------------------------------------------------------------
__global__ __launch_bounds__(256, 2) void mlp_kernel(
    const short* __restrict__ hs,
    const short* __restrict__ W1p, const float* __restrict__ b1p,
    const short* __restrict__ W2p, const float* __restrict__ b2,
    const short* __restrict__ W3p, const float* __restrict__ b3,
    const float* __restrict__ W4,  const float* __restrict__ b4,
    float* __restrict__ out)
{
    __shared__ __align__(16) short a1[32][584];
    __shared__ __align__(16) short a2[32][264];
    __shared__ __align__(16) short a3[32][72];
    const int tid  = threadIdx.x;
    const int w    = tid >> 6;
    const int lane = tid & 63;
    const int quad = lane >> 4;
    const int c16  = lane & 15;
    const int m0   = blockIdx.x * 32;
    const int mtile = blockIdx.x * 2;

    {
        f32x4 acc[2][9];
#pragma unroll
        for (int mt = 0; mt < 2; ++mt)
#pragma unroll
            for (int i = 0; i < 9; ++i)
                acc[mt][i] = (f32x4){0.f, 0.f, 0.f, 0.f};
#pragma unroll 4
        for (int ks = 0; ks < 20; ++ks) {
            short8 a[2];
#pragma unroll
            for (int mt = 0; mt < 2; ++mt)
                a[mt] = *(const short8*)&hs[(((mtile + mt) * 20 + ks) << 9) + lane * 8];
#pragma unroll
            for (int i = 0; i < 9; ++i) {
                short8 b = *(const short8*)&W1p[(((w * 9 + i) * 20 + ks) << 9) + lane * 8];
                acc[0][i] = MFMA(a[0], b, acc[0][i]);
                acc[1][i] = MFMA(a[1], b, acc[1][i]);
            }
        }
#pragma unroll
        for (int i = 0; i < 9; ++i) {
            int n = (w * 9 + i) * 16 + c16;
            float bv = b1p[n];
#pragma unroll
            for (int mt = 0; mt < 2; ++mt)
#pragma unroll
                for (int r = 0; r < 4; ++r) {
                    int m = mt * 16 + quad * 4 + r;
                    float v = acc[mt][i][r] + bv;
                    a1[m][n] = f2bs(v > 0.f ? v : 0.f);
                }
        }
    }
    __syncthreads();

    {
        f32x4 acc[2][4];
#pragma unroll
        for (int mt = 0; mt < 2; ++mt)
#pragma unroll
            for (int i = 0; i < 4; ++i)
                acc[mt][i] = (f32x4){0.f, 0.f, 0.f, 0.f};
#pragma unroll 4
        for (int ks = 0; ks < 17; ++ks) {
            short8 a[2];
#pragma unroll
            for (int mt = 0; mt < 2; ++mt)
                a[mt] = *(const short8*)&a1[mt * 16 + c16][ks * 32 + quad * 8];
#pragma unroll
            for (int i = 0; i < 4; ++i) {
                short8 b = *(const short8*)&W2p[(((w * 4 + i) * 17 + ks) << 9) + lane * 8];
                acc[0][i] = MFMA(a[0], b, acc[0][i]);
                acc[1][i] = MFMA(a[1], b, acc[1][i]);
            }
        }
#pragma unroll
        for (int i = 0; i < 4; ++i) {
            int n = (w * 4 + i) * 16 + c16;
            float bv = b2[n];
#pragma unroll
            for (int mt = 0; mt < 2; ++mt)
#pragma unroll
                for (int r = 0; r < 4; ++r) {
                    int m = mt * 16 + quad * 4 + r;
                    float v = acc[mt][i][r] + bv;
                    a2[m][n] = f2bs(v > 0.f ? v : 0.f);
                }
        }
    }
    __syncthreads();

    {
        f32x4 acc[2];
        acc[0] = (f32x4){0.f, 0.f, 0.f, 0.f};
        acc[1] = (f32x4){0.f, 0.f, 0.f, 0.f};
#pragma unroll
        for (int ks = 0; ks < 8; ++ks) {
            short8 a[2];
#pragma unroll
            for (int mt = 0; mt < 2; ++mt)
                a[mt] = *(const short8*)&a2[mt * 16 + c16][ks * 32 + quad * 8];
            short8 b = *(const short8*)&W3p[((w * 8 + ks) << 9) + lane * 8];
            acc[0] = MFMA(a[0], b, acc[0]);
            acc[1] = MFMA(a[1], b, acc[1]);
        }
        int n = w * 16 + c16;
        float bv = b3[n];
#pragma unroll
        for (int mt = 0; mt < 2; ++mt)
#pragma unroll
            for (int r = 0; r < 4; ++r) {
                int m = mt * 16 + quad * 4 + r;
                float v = acc[mt][r] + bv;
                a3[m][n] = f2bs(v > 0.f ? v : 0.f);
            }
    }
    __syncthreads();

    if (tid < 64) {
        int m   = tid >> 1;
        int cls = tid & 1;
        float s = b4[cls];
#pragma unroll 8
        for (int k = 0; k < 64; ++k)
            s += b2f(a3[m][k]) * W4[cls * 64 + k];
        float other = __shfl_xor(s, 1);
        float p = 1.f / (1.f + __expf(other - s));
        out[(m0 + m) * 2 + cls] = p;
    }
}

// ---------------------------------------------------------------------------
extern "C" void kernel_launch(void* const* d_in, const int* in_sizes, int n_in,
                              void* d_out, int out_size, void* d_ws, size_t ws_size,
                              hipStream_t stream)
{
    (void)in_sizes; (void)n_in; (void)out_size;
    if (ws_size < (size_t)WS_NEED) return;

    const float* x1   = (const float*)d_in[0];
    const float* x2   = (const float*)d_in[1];
    const float* W_ih = (const float*)d_in[2];
    const float* W_hh = (const float*)d_in[3];
    const float* b_ih = (const float*)d_in[4];
    const float* b_hh = (const float*)d_in[5];
    const float* W1   = (const float*)d_in[6];
    const float* b1   = (const float*)d_in[7];
    const float* W2   = (const float*)d_in[8];
    const float* b2   = (const float*)d_in[9];
    const float* W3   = (const float*)d_in[10];
    const float* b3   = (const float*)d_in[11];
    const float* W4   = (const float*)d_in[12];
    const float* b4   = (const float*)d_in[13];

    char* ws = (char*)d_ws;
    short* Wihp  = (short*)(ws + O_WIH);
    short* Whhp  = (short*)(ws + O_WHH);
    short* W1p   = (short*)(ws + O_W1);
    short* W2p   = (short*)(ws + O_W2);
    short* W3p   = (short*)(ws + O_W3);
    float* biasg = (float*)(ws + O_BG);
    float* b1p   = (float*)(ws + O_B1);
    short* xg    = (short*)(ws + O_XG);
    short* hsb   = (short*)(ws + O_HS);

    prep_kernel<<<3461, 256, 0, stream>>>(W_ih, W_hh, b_ih, b_hh, W1, b1, W2, W3,
                                          Wihp, Whhp, biasg, W1p, b1p, W2p, W3p);
    k1_xgemm<<<2560, 256, 0, stream>>>(x1, x2, Wihp, biasg, xg);
    k2_rec<<<512, 512, 0, stream>>>(Whhp, xg, hsb);
    mlp_kernel<<<512, 256, 0, stream>>>(hsb, W1p, b1p, W2p, b2, W3p, b3, W4, b4,
                                        (float*)d_out);
}